// Round 5
// baseline (644.576 us; speedup 1.0000x reference)
//
#include <hip/hip_runtime.h>

typedef short v8s __attribute__((ext_vector_type(8)));
typedef float v4f __attribute__((ext_vector_type(4)));

#define NBH      2000          // 500 areas * 4 heads
#define LSEQ     200
#define LPAD     208
#define DEPTH    32
#define DMODEL   128
#define TEU      399
#define MASKNEG  (-6550.4f)
#define QSCALE   0.08838834764831845f   // 1/sqrt(128)

// workspace layout, in ushort (bf16) elements
#define BH_ELE   (LPAD * DEPTH)              // 6656
#define QW_OFF   0
#define KW_OFF   (NBH * BH_ELE)              // 13,312,000
#define VW_OFF   (2 * NBH * BH_ELE)
#define WT_OFF   (3 * NBH * BH_ELE)          // 39,936,000
#define EU_OFF   (WT_OFF + 3 * DMODEL * DMODEL)

__device__ __forceinline__ unsigned short f2b(float f) {
  // round-to-nearest-even f32 -> bf16 (no NaN care needed on valid data)
  unsigned u = __float_as_uint(f);
  unsigned r = 0x7fffu + ((u >> 16) & 1u);
  return (unsigned short)((u + r) >> 16);
}
__device__ __forceinline__ float b2f(unsigned short u) {
  return __uint_as_float(((unsigned)u) << 16);
}

// ---------------- kernel 0: prep WT (transposed bf16 weights) + Eu ----------------
__global__ void prep_kernel(const float* __restrict__ Wq, const float* __restrict__ Wk,
                            const float* __restrict__ Wv, const float* __restrict__ E,
                            unsigned short* __restrict__ ws) {
  unsigned short* WT = ws + WT_OFF;
  unsigned short* Eu = ws + EU_OFF;
  const int nW = 3 * DMODEL * DMODEL;
  const int total = nW + TEU * DEPTH;
  for (int i = blockIdx.x * blockDim.x + threadIdx.x; i < total; i += gridDim.x * blockDim.x) {
    if (i < nW) {
      int m = i >> 14; int r = i & 16383; int e = r >> 7; int kk = r & 127;
      const float* W = (m == 0) ? Wq : ((m == 1) ? Wk : Wv);
      WT[i] = f2b(W[kk * DMODEL + e]);          // WT[m][e][k] = W[k][e]
    } else {
      int j = i - nW;                            // t*32 + d
      Eu[j] = f2b(E[2 * DEPTH + j]);             // Eu = E[2:]
    }
  }
}

// ---------------- kernel 1: q/k/v projection (bf16 MFMA), q pre-scaled ----------------
__global__ __launch_bounds__(256, 4)
void proj_kernel(const float* __restrict__ x, const float* __restrict__ bq,
                 const float* __restrict__ bk, const float* __restrict__ bv,
                 unsigned short* __restrict__ ws) {
  const unsigned short* WT = ws + WT_OFF;
  int bh = blockIdx.x; int a = bh >> 2; int h = bh & 3;
  int tid = threadIdx.x; int wave = tid >> 6; int lane = tid & 63;
  int g = lane >> 4; int c = lane & 15;

  for (int st = wave; st < 13; st += 4) {
    int l0 = st * 16;
    int row = a * LSEQ + min(l0 + c, LSEQ - 1);   // clamp pad rows (outputs zeroed)
    v8s afr[4];
#pragma unroll
    for (int ks = 0; ks < 4; ++ks) {
      const float* p = x + (size_t)row * DMODEL + ks * 32 + 8 * g;
      float4 f0 = *(const float4*)p;
      float4 f1 = *(const float4*)(p + 4);
      v8s t;
      t[0] = (short)f2b(f0.x); t[1] = (short)f2b(f0.y); t[2] = (short)f2b(f0.z); t[3] = (short)f2b(f0.w);
      t[4] = (short)f2b(f1.x); t[5] = (short)f2b(f1.y); t[6] = (short)f2b(f1.z); t[7] = (short)f2b(f1.w);
      afr[ks] = t;
    }
#pragma unroll
    for (int m = 0; m < 3; ++m) {
      const float* bp = (m == 0) ? bq : ((m == 1) ? bk : bv);
#pragma unroll
      for (int nt = 0; nt < 2; ++nt) {
        int col = h * DEPTH + nt * 16 + c;        // column in D_MODEL
        v4f acc = {0.f, 0.f, 0.f, 0.f};
#pragma unroll
        for (int ks = 0; ks < 4; ++ks) {
          v8s bfr = *(const v8s*)(WT + ((size_t)(m * DMODEL + col)) * DMODEL + ks * 32 + 8 * g);
          acc = __builtin_amdgcn_mfma_f32_16x16x32_bf16(afr[ks], bfr, acc, 0, 0, 0);
        }
        float bias = bp[col];
        if (m < 2) {
          unsigned short* dst = ws + (m == 0 ? QW_OFF : KW_OFF) + (size_t)bh * BH_ELE
                                + (size_t)l0 * DEPTH + nt * 16 + c;
#pragma unroll
          for (int r = 0; r < 4; ++r) {
            int ll = 4 * g + r;
            float val = acc[r] + bias;
            if (m == 0) val *= QSCALE;
            dst[ll * DEPTH] = (l0 + ll < LSEQ) ? f2b(val) : (unsigned short)0;
          }
        } else {
          // v stored transposed: vT[bh][d][l], 4 consecutive l per lane -> 8B store
          ushort4 pk;
          float v0 = acc[0] + bias, v1 = acc[1] + bias, v2 = acc[2] + bias, v3 = acc[3] + bias;
          int lb = l0 + 4 * g;
          pk.x = (lb + 0 < LSEQ) ? f2b(v0) : (unsigned short)0;
          pk.y = (lb + 1 < LSEQ) ? f2b(v1) : (unsigned short)0;
          pk.z = (lb + 2 < LSEQ) ? f2b(v2) : (unsigned short)0;
          pk.w = (lb + 3 < LSEQ) ? f2b(v3) : (unsigned short)0;
          *(ushort4*)(ws + VW_OFF + (size_t)bh * BH_ELE + (size_t)(nt * 16 + c) * LPAD + lb) = pk;
        }
      }
    }
  }
}

// ---------------- kernel 2: fused rel-shift attention ----------------
__global__ __launch_bounds__(256, 2)
void attn_kernel(const unsigned short* __restrict__ ws, const float* __restrict__ maskp,
                 float* __restrict__ o) {
  __shared__ __align__(16) unsigned short k_lds[LPAD * 40];    // [208][40] pitch, 2-way max
  __shared__ __align__(16) unsigned short vT_lds[DEPTH * 216]; // [32][216]
  __shared__ __align__(16) unsigned short srel[4][16 * 212];   // per-wave [16][212]; reused as P [16][40]

  int bh = blockIdx.x; int a = bh >> 2; int h = bh & 3;
  int tid = threadIdx.x; int wave = tid >> 6; int lane = tid & 63;
  int g = lane >> 4; int c = lane & 15;

  const unsigned short* qws = ws + QW_OFF + (size_t)bh * BH_ELE;
  const unsigned short* kws = ws + KW_OFF + (size_t)bh * BH_ELE;
  const unsigned short* vws = ws + VW_OFF + (size_t)bh * BH_ELE;
  const unsigned short* eu  = ws + EU_OFF;

  // stage k [208][32] -> [208][40]
  for (int i = tid; i < LPAD * 4; i += 256) {
    int r = i >> 2, cc = i & 3;
    uint4 v = *(const uint4*)(kws + r * 32 + cc * 8);
    *(uint4*)&k_lds[r * 40 + cc * 8] = v;
  }
  // stage vT [32][208] -> [32][216]
  for (int i = tid; i < DEPTH * 26; i += 256) {
    int r = i / 26, cc = i - r * 26;
    uint4 v = *(const uint4*)(vws + r * LPAD + cc * 8);
    *(uint4*)&vT_lds[r * 216 + cc * 8] = v;
  }
  __syncthreads();

  float* attn_base = o + 12800000 + (size_t)bh * 40000;
  unsigned short* sw = srel[wave];

  for (int st = wave; st < 13; st += 4) {
    int l0 = st * 16;
    v8s aq = *(const v8s*)(qws + (size_t)(l0 + c) * DEPTH + 8 * g);  // q A-frag, reused

    // ---- QE band (MFMA over Eu) scattered into shift-order Srel[l][j] ----
    int TB0 = max(0, 184 - l0);
    int ntt = (398 - l0 - TB0 + 16) >> 4;
    for (int tt = 0; tt < ntt; ++tt) {
      int t = TB0 + tt * 16 + c;
      int tc = min(t, 398);
      v8s be = *(const v8s*)(eu + (size_t)tc * DEPTH + 8 * g);
      v4f z = {0.f, 0.f, 0.f, 0.f};
      v4f qe = __builtin_amdgcn_mfma_f32_16x16x32_bf16(aq, be, z, 0, 0, 0);
#pragma unroll
      for (int r = 0; r < 4; ++r) {
        int j = t - 199 + l0 + 4 * g + r;        // Srel[l][j] = QE[l][199+j-l]
        if (j >= 0 && j < LSEQ) sw[(4 * g + r) * 212 + j] = f2b(qe[r]);
      }
    }

    // ---- qk + assemble logits ----
    v4f S[13];
#pragma unroll
    for (int jt = 0; jt < 13; ++jt) {
      v8s bk_ = *(const v8s*)&k_lds[(jt * 16 + c) * 40 + 8 * g];
      v4f z = {0.f, 0.f, 0.f, 0.f};
      S[jt] = __builtin_amdgcn_mfma_f32_16x16x32_bf16(aq, bk_, z, 0, 0, 0);
    }
#pragma unroll
    for (int jt = 0; jt < 13; ++jt) {
      int j = jt * 16 + c;
      int jc = min(j, LSEQ - 1);
      bool jv = (j < LSEQ);
#pragma unroll
      for (int r = 0; r < 4; ++r) {
        int l = l0 + 4 * g + r;
        float sr = jv ? b2f(sw[(4 * g + r) * 212 + j]) : 0.f;
        float mv = maskp[min(l, LSEQ - 1) * LSEQ + jc];
        S[jt][r] += sr + mv * MASKNEG;
        if (!jv) S[jt][r] = -1e30f;              // pad cols -> exp==0
      }
    }

    // ---- softmax (rows live across the 16-lane group) ----
    float invs[4];
#pragma unroll
    for (int r = 0; r < 4; ++r) {
      float mx = -1e30f;
#pragma unroll
      for (int jt = 0; jt < 13; ++jt) mx = fmaxf(mx, S[jt][r]);
#pragma unroll
      for (int d = 1; d < 16; d <<= 1) mx = fmaxf(mx, __shfl_xor(mx, d, 64));
      float sum = 0.f;
#pragma unroll
      for (int jt = 0; jt < 13; ++jt) { float e = __expf(S[jt][r] - mx); S[jt][r] = e; sum += e; }
#pragma unroll
      for (int d = 1; d < 16; d <<= 1) sum += __shfl_xor(sum, d, 64);
      invs[r] = 1.f / sum;
    }

    // ---- attn store (f32) + PV via LDS-transposed P tiles ----
    v4f oacc0 = {0.f, 0.f, 0.f, 0.f}, oacc1 = {0.f, 0.f, 0.f, 0.f};
#pragma unroll
    for (int jp = 0; jp < 7; ++jp) {
#pragma unroll
      for (int half = 0; half < 2; ++half) {
        int jt = 2 * jp + half;
#pragma unroll
        for (int r = 0; r < 4; ++r) {
          int ll = 4 * g + r;
          float p = 0.f;
          if (jt < 13) {
            p = S[jt][r] * invs[r];
            int l = l0 + ll; int j = jt * 16 + c;
            if (l < LSEQ && j < LSEQ) attn_base[l * LSEQ + j] = p;
          }
          sw[ll * 40 + half * 16 + c] = (jt < 13) ? f2b(p) : (unsigned short)0;
        }
      }
      v8s ap = *(const v8s*)&sw[c * 40 + 8 * g];
      int col0 = min(jp * 32 + 8 * g, 200);       // clamp: zero-padded v cols, A-side already 0
      v8s bv0 = *(const v8s*)&vT_lds[c * 216 + col0];
      v8s bv1 = *(const v8s*)&vT_lds[(16 + c) * 216 + col0];
      oacc0 = __builtin_amdgcn_mfma_f32_16x16x32_bf16(ap, bv0, oacc0, 0, 0, 0);
      oacc1 = __builtin_amdgcn_mfma_f32_16x16x32_bf16(ap, bv1, oacc1, 0, 0, 0);
    }

    // ---- out store ----
#pragma unroll
    for (int r = 0; r < 4; ++r) {
      int l = l0 + 4 * g + r;
      if (l < LSEQ) {
        float* op = o + ((size_t)(a * LSEQ + l)) * DMODEL + h * DEPTH;
        op[c] = oacc0[r];
        op[16 + c] = oacc1[r];
      }
    }
  }
}

extern "C" void kernel_launch(void* const* d_in, const int* in_sizes, int n_in,
                              void* d_out, int out_size, void* d_ws, size_t ws_size,
                              hipStream_t stream) {
  const float* inp   = (const float*)d_in[0];
  const float* maskp = (const float*)d_in[1];
  const float* Wq    = (const float*)d_in[2];
  const float* bq    = (const float*)d_in[3];
  const float* Wk    = (const float*)d_in[4];
  const float* bk    = (const float*)d_in[5];
  const float* Wv    = (const float*)d_in[6];
  const float* bv    = (const float*)d_in[7];
  const float* E     = (const float*)d_in[8];
  unsigned short* ws = (unsigned short*)d_ws;   // ~76.3 MiB used
  float* o = (float*)d_out;

  prep_kernel<<<242, 256, 0, stream>>>(Wq, Wk, Wv, E, ws);
  proj_kernel<<<NBH, 256, 0, stream>>>(inp, bq, bk, bv, ws);
  attn_kernel<<<NBH, 256, 0, stream>>>(ws, maskp, o);
}

// Round 7
// 557.535 us; speedup vs baseline: 1.1561x; 1.1561x over previous
//
#include <hip/hip_runtime.h>

typedef short v8s __attribute__((ext_vector_type(8)));
typedef float v4f __attribute__((ext_vector_type(4)));

#define NBH      2000          // 500 areas * 4 heads
#define LSEQ     200
#define LPAD     208
#define DEPTH    32
#define DMODEL   128
#define TEU      399
#define MASKNEG  (-6550.4f)
#define QSCALE   0.08838834764831845f   // 1/sqrt(128)

// workspace layout, in ushort (bf16) elements
#define BH_ELE   (LPAD * DEPTH)              // 6656
#define QW_OFF   0
#define KW_OFF   (NBH * BH_ELE)              // 13,312,000
#define VW_OFF   (2 * NBH * BH_ELE)
#define WT_OFF   (3 * NBH * BH_ELE)          // 39,936,000
#define EU_OFF   (WT_OFF + 3 * DMODEL * DMODEL)

__device__ __forceinline__ unsigned short f2b(float f) {
  unsigned u = __float_as_uint(f);
  unsigned r = 0x7fffu + ((u >> 16) & 1u);
  return (unsigned short)((u + r) >> 16);
}
__device__ __forceinline__ float b2f(unsigned short u) {
  return __uint_as_float(((unsigned)u) << 16);
}

// ---------------- kernel 0: prep WT (transposed bf16 weights) + Eu ----------------
__global__ void prep_kernel(const float* __restrict__ Wq, const float* __restrict__ Wk,
                            const float* __restrict__ Wv, const float* __restrict__ E,
                            unsigned short* __restrict__ ws) {
  unsigned short* WT = ws + WT_OFF;
  unsigned short* Eu = ws + EU_OFF;
  const int nW = 3 * DMODEL * DMODEL;
  const int total = nW + TEU * DEPTH;
  for (int i = blockIdx.x * blockDim.x + threadIdx.x; i < total; i += gridDim.x * blockDim.x) {
    if (i < nW) {
      int m = i >> 14; int r = i & 16383; int e = r >> 7; int kk = r & 127;
      const float* W = (m == 0) ? Wq : ((m == 1) ? Wk : Wv);
      WT[i] = f2b(W[kk * DMODEL + e]);          // WT[m][e][k] = W[k][e]
    } else {
      int j = i - nW;                            // t*32 + d
      Eu[j] = f2b(E[2 * DEPTH + j]);             // Eu = E[2:]
    }
  }
}

// ---------------- kernel 1: per-AREA q/k/v projection (x staged once in LDS) ----------------
// block = area (500 blocks). x read 1x (was 4x), coalesced staging; B-frags hoisted out of
// the stripe loop; vT assembled in LDS and written out with coalesced 16B rows.
__global__ __launch_bounds__(256, 2)
void proj_kernel(const float* __restrict__ x, const float* __restrict__ bq,
                 const float* __restrict__ bk, const float* __restrict__ bv,
                 unsigned short* __restrict__ ws) {
  __shared__ __align__(16) unsigned short x_lds[LPAD * 136];   // 56.6 KB, pitch 136 (16B-aligned rows, 2-way banks)
  __shared__ __align__(16) unsigned short vt_lds[DEPTH * 216]; // 13.8 KB

  const unsigned short* WT = ws + WT_OFF;
  int a = blockIdx.x;
  int tid = threadIdx.x; int wave = tid >> 6; int lane = tid & 63;
  int g = lane >> 4; int c = lane & 15;

  // stage x area -> bf16 LDS [208][136]; pad rows zeroed
  for (int i = tid; i < LPAD * 16; i += 256) {
    int row = i >> 4; int col = (i & 15) * 8;
    v8s t = {0, 0, 0, 0, 0, 0, 0, 0};
    if (row < LSEQ) {
      const float* p = x + ((size_t)(a * LSEQ + row)) * DMODEL + col;
      float4 f0 = *(const float4*)p;
      float4 f1 = *(const float4*)(p + 4);
      t[0] = (short)f2b(f0.x); t[1] = (short)f2b(f0.y); t[2] = (short)f2b(f0.z); t[3] = (short)f2b(f0.w);
      t[4] = (short)f2b(f1.x); t[5] = (short)f2b(f1.y); t[6] = (short)f2b(f1.z); t[7] = (short)f2b(f1.w);
    }
    *(v8s*)&x_lds[row * 136 + col] = t;
  }
  __syncthreads();

  for (int h = 0; h < 4; ++h) {
    int bh = a * 4 + h;
    // ---- q and k ----
#pragma unroll
    for (int m = 0; m < 2; ++m) {
      const float* bp = (m == 0) ? bq : bk;
      unsigned short* dstbase = ws + (m == 0 ? QW_OFF : KW_OFF) + (size_t)bh * BH_ELE;
#pragma unroll
      for (int nt = 0; nt < 2; ++nt) {
        int col = h * DEPTH + nt * 16 + c;
        v8s bfr[4];
#pragma unroll
        for (int ks = 0; ks < 4; ++ks)
          bfr[ks] = *(const v8s*)(WT + ((size_t)(m * DMODEL + col)) * DMODEL + ks * 32 + 8 * g);
        float bias = bp[col];
        for (int st = wave; st < 13; st += 4) {
          int l0 = st * 16;
          v4f acc = {0.f, 0.f, 0.f, 0.f};
#pragma unroll
          for (int ks = 0; ks < 4; ++ks) {
            v8s afr = *(const v8s*)&x_lds[(l0 + c) * 136 + ks * 32 + 8 * g];
            acc = __builtin_amdgcn_mfma_f32_16x16x32_bf16(afr, bfr[ks], acc, 0, 0, 0);
          }
#pragma unroll
          for (int r = 0; r < 4; ++r) {
            int ll = 4 * g + r;
            float val = acc[r] + bias;
            if (m == 0) val *= QSCALE;
            dstbase[(size_t)(l0 + ll) * DEPTH + nt * 16 + c] =
                (l0 + ll < LSEQ) ? f2b(val) : (unsigned short)0;
          }
        }
      }
    }
    // ---- v (into LDS transpose buffer) ----
#pragma unroll
    for (int nt = 0; nt < 2; ++nt) {
      int col = h * DEPTH + nt * 16 + c;
      v8s bfr[4];
#pragma unroll
      for (int ks = 0; ks < 4; ++ks)
        bfr[ks] = *(const v8s*)(WT + ((size_t)(2 * DMODEL + col)) * DMODEL + ks * 32 + 8 * g);
      float bias = bv[col];
      for (int st = wave; st < 13; st += 4) {
        int l0 = st * 16;
        v4f acc = {0.f, 0.f, 0.f, 0.f};
#pragma unroll
        for (int ks = 0; ks < 4; ++ks) {
          v8s afr = *(const v8s*)&x_lds[(l0 + c) * 136 + ks * 32 + 8 * g];
          acc = __builtin_amdgcn_mfma_f32_16x16x32_bf16(afr, bfr[ks], acc, 0, 0, 0);
        }
        ushort4 pk;
        int lb = l0 + 4 * g;
        pk.x = (lb + 0 < LSEQ) ? f2b(acc[0] + bias) : (unsigned short)0;
        pk.y = (lb + 1 < LSEQ) ? f2b(acc[1] + bias) : (unsigned short)0;
        pk.z = (lb + 2 < LSEQ) ? f2b(acc[2] + bias) : (unsigned short)0;
        pk.w = (lb + 3 < LSEQ) ? f2b(acc[3] + bias) : (unsigned short)0;
        *(ushort4*)&vt_lds[(nt * 16 + c) * 216 + lb] = pk;
      }
    }
    __syncthreads();
    // coalesced vT writeout: rows d (pitch 208), 16B chunks
    for (int i = tid; i < DEPTH * 26; i += 256) {
      int r = i / 26, cc = i - r * 26;
      *(uint4*)(ws + VW_OFF + (size_t)bh * BH_ELE + (size_t)r * LPAD + cc * 8) =
          *(const uint4*)&vt_lds[r * 216 + cc * 8];
    }
    __syncthreads();   // before next head reuses vt_lds
  }
}

// ---------------- kernel 2: fused rel-shift attention ----------------
__global__ __launch_bounds__(256, 2)
void attn_kernel(const unsigned short* __restrict__ ws, const float* __restrict__ maskp,
                 float* __restrict__ o) {
  __shared__ __align__(16) unsigned short k_lds[LPAD * 40];    // [208][40]
  __shared__ __align__(16) unsigned short vT_lds[DEPTH * 216]; // [32][216]
  __shared__ __align__(16) unsigned short srel[4][16 * 212];   // per-wave; reused as P [16][40]

  int bh = blockIdx.x; int a = bh >> 2; int h = bh & 3;
  int tid = threadIdx.x; int wave = tid >> 6; int lane = tid & 63;
  int g = lane >> 4; int c = lane & 15;
  (void)h;

  const unsigned short* qws = ws + QW_OFF + (size_t)bh * BH_ELE;
  const unsigned short* kws = ws + KW_OFF + (size_t)bh * BH_ELE;
  const unsigned short* vws = ws + VW_OFF + (size_t)bh * BH_ELE;
  const unsigned short* eu  = ws + EU_OFF;

  for (int i = tid; i < LPAD * 4; i += 256) {
    int r = i >> 2, cc = i & 3;
    uint4 v = *(const uint4*)(kws + r * 32 + cc * 8);
    *(uint4*)&k_lds[r * 40 + cc * 8] = v;
  }
  for (int i = tid; i < DEPTH * 26; i += 256) {
    int r = i / 26, cc = i - r * 26;
    uint4 v = *(const uint4*)(vws + (size_t)r * LPAD + cc * 8);
    *(uint4*)&vT_lds[r * 216 + cc * 8] = v;
  }
  __syncthreads();

  float* attn_base = o + 12800000 + (size_t)bh * 40000;
  unsigned short* sw = srel[wave];

  for (int st = wave; st < 13; st += 4) {
    int l0 = st * 16;
    v8s aq = *(const v8s*)(qws + (size_t)(l0 + c) * DEPTH + 8 * g);

    // ---- QE band: compile-time 14 tiles, loads batched 7-deep for pipelining ----
    // For l0==192 the 14th tile scatters nothing (j>=201 always); clamped loads only
    // corrupt MFMA output columns whose scatters are skipped (j>=200).
    int TB0 = max(0, 184 - l0);
    v8s beA[7];
#pragma unroll
    for (int tt = 0; tt < 7; ++tt)
      beA[tt] = *(const v8s*)(eu + (size_t)min(TB0 + tt * 16 + c, 398) * DEPTH + 8 * g);
#pragma unroll
    for (int tt = 0; tt < 7; ++tt) {
      v4f z = {0.f, 0.f, 0.f, 0.f};
      v4f qe = __builtin_amdgcn_mfma_f32_16x16x32_bf16(aq, beA[tt], z, 0, 0, 0);
      int t = TB0 + tt * 16 + c;
#pragma unroll
      for (int r = 0; r < 4; ++r) {
        int j = t - 199 + l0 + 4 * g + r;
        if (j >= 0 && j < LSEQ) sw[(4 * g + r) * 212 + j] = f2b(qe[r]);
      }
    }
#pragma unroll
    for (int tt = 7; tt < 14; ++tt)
      beA[tt - 7] = *(const v8s*)(eu + (size_t)min(TB0 + tt * 16 + c, 398) * DEPTH + 8 * g);
#pragma unroll
    for (int tt = 7; tt < 14; ++tt) {
      v4f z = {0.f, 0.f, 0.f, 0.f};
      v4f qe = __builtin_amdgcn_mfma_f32_16x16x32_bf16(aq, beA[tt - 7], z, 0, 0, 0);
      int t = TB0 + tt * 16 + c;
#pragma unroll
      for (int r = 0; r < 4; ++r) {
        int j = t - 199 + l0 + 4 * g + r;
        if (j >= 0 && j < LSEQ) sw[(4 * g + r) * 212 + j] = f2b(qe[r]);
      }
    }

    // ---- qk + assemble logits ----
    v4f S[13];
#pragma unroll
    for (int jt = 0; jt < 13; ++jt) {
      v8s bk_ = *(const v8s*)&k_lds[(jt * 16 + c) * 40 + 8 * g];
      v4f z = {0.f, 0.f, 0.f, 0.f};
      S[jt] = __builtin_amdgcn_mfma_f32_16x16x32_bf16(aq, bk_, z, 0, 0, 0);
    }
#pragma unroll
    for (int jt = 0; jt < 13; ++jt) {
      int j = jt * 16 + c;
      int jc = min(j, LSEQ - 1);
      bool jv = (j < LSEQ);
#pragma unroll
      for (int r = 0; r < 4; ++r) {
        int l = l0 + 4 * g + r;
        float sr = jv ? b2f(sw[(4 * g + r) * 212 + j]) : 0.f;
        float mv = maskp[min(l, LSEQ - 1) * LSEQ + jc];
        S[jt][r] += sr + mv * MASKNEG;
        if (!jv) S[jt][r] = -1e30f;
      }
    }

    // ---- softmax ----
    float invs[4];
#pragma unroll
    for (int r = 0; r < 4; ++r) {
      float mx = -1e30f;
#pragma unroll
      for (int jt = 0; jt < 13; ++jt) mx = fmaxf(mx, S[jt][r]);
#pragma unroll
      for (int d = 1; d < 16; d <<= 1) mx = fmaxf(mx, __shfl_xor(mx, d, 64));
      float sum = 0.f;
#pragma unroll
      for (int jt = 0; jt < 13; ++jt) { float e = __expf(S[jt][r] - mx); S[jt][r] = e; sum += e; }
#pragma unroll
      for (int d = 1; d < 16; d <<= 1) sum += __shfl_xor(sum, d, 64);
      invs[r] = 1.f / sum;
    }

    // ---- attn store + PV ----
    v4f oacc0 = {0.f, 0.f, 0.f, 0.f}, oacc1 = {0.f, 0.f, 0.f, 0.f};
#pragma unroll
    for (int jp = 0; jp < 7; ++jp) {
#pragma unroll
      for (int half = 0; half < 2; ++half) {
        int jt = 2 * jp + half;
#pragma unroll
        for (int r = 0; r < 4; ++r) {
          int ll = 4 * g + r;
          float p = 0.f;
          if (jt < 13) {
            p = S[jt][r] * invs[r];
            int l = l0 + ll; int j = jt * 16 + c;
            if (l < LSEQ && j < LSEQ) attn_base[l * LSEQ + j] = p;
          }
          sw[ll * 40 + half * 16 + c] = (jt < 13) ? f2b(p) : (unsigned short)0;
        }
      }
      v8s ap = *(const v8s*)&sw[c * 40 + 8 * g];
      int col0 = min(jp * 32 + 8 * g, 200);
      v8s bv0 = *(const v8s*)&vT_lds[c * 216 + col0];
      v8s bv1 = *(const v8s*)&vT_lds[(16 + c) * 216 + col0];
      oacc0 = __builtin_amdgcn_mfma_f32_16x16x32_bf16(ap, bv0, oacc0, 0, 0, 0);
      oacc1 = __builtin_amdgcn_mfma_f32_16x16x32_bf16(ap, bv1, oacc1, 0, 0, 0);
    }

    // ---- out store ----
#pragma unroll
    for (int r = 0; r < 4; ++r) {
      int l = l0 + 4 * g + r;
      if (l < LSEQ) {
        float* op = o + ((size_t)(a * LSEQ + l)) * DMODEL + (bh & 3) * DEPTH;
        op[c] = oacc0[r];
        op[16 + c] = oacc1[r];
      }
    }
  }
}

extern "C" void kernel_launch(void* const* d_in, const int* in_sizes, int n_in,
                              void* d_out, int out_size, void* d_ws, size_t ws_size,
                              hipStream_t stream) {
  const float* inp   = (const float*)d_in[0];
  const float* maskp = (const float*)d_in[1];
  const float* Wq    = (const float*)d_in[2];
  const float* bq    = (const float*)d_in[3];
  const float* Wk    = (const float*)d_in[4];
  const float* bk    = (const float*)d_in[5];
  const float* Wv    = (const float*)d_in[6];
  const float* bv    = (const float*)d_in[7];
  const float* E     = (const float*)d_in[8];
  unsigned short* ws = (unsigned short*)d_ws;   // ~76.3 MiB used
  float* o = (float*)d_out;

  prep_kernel<<<242, 256, 0, stream>>>(Wq, Wk, Wv, E, ws);
  proj_kernel<<<500, 256, 0, stream>>>(inp, bq, bk, bv, ws);
  attn_kernel<<<NBH, 256, 0, stream>>>(ws, maskp, o);
}